// Round 3
// baseline (923.581 us; speedup 1.0000x reference)
//
#include <hip/hip_runtime.h>
#include <math.h>

#define NUM_BINS 20
#define NB       1024              // histogram buckets over p in [0,1)
#define NH       (3 * NB)          // floats per block histogram: [n | sum_p | sum_t]
#define BLOCK    256
#define MAXBLK   1024

// K1 = -1/(T*ln2) with T=0.1, so exp(-d^2/T) = exp2(K1*d*d)
#define K1C (-14.426950408889634f)

__device__ __forceinline__ void acc_elem(float pp, float tt,
                                         float* hN, float* hP, float* hT) {
    unsigned b = (unsigned)(pp * (float)NB);
    if (b > NB - 1) b = NB - 1;
    atomicAdd(&hN[b], 1.0f);   // ds_add_f32, result unused -> no-return form
    atomicAdd(&hP[b], pp);
    atomicAdd(&hT[b], tt);
}

__global__ __launch_bounds__(BLOCK) void ace_hist(const float* __restrict__ p,
                                                  const float* __restrict__ t,
                                                  float* __restrict__ partials,
                                                  int n4, int nblk) {
    __shared__ float hN[NB];
    __shared__ float hP[NB];
    __shared__ float hT[NB];
    for (int i = threadIdx.x; i < NB; i += BLOCK) { hN[i] = 0.f; hP[i] = 0.f; hT[i] = 0.f; }
    __syncthreads();

    const float4* __restrict__ p4 = (const float4*)p;
    const float4* __restrict__ t4 = (const float4*)t;

    int tid    = blockIdx.x * BLOCK + threadIdx.x;
    int stride = nblk * BLOCK;

    // 2-deep batching: 4 independent dwordx4 loads in flight per iteration
    int i0 = tid;
    for (; i0 + stride < n4; i0 += 2 * stride) {
        float4 a0 = p4[i0];
        float4 b0 = t4[i0];
        float4 a1 = p4[i0 + stride];
        float4 b1 = t4[i0 + stride];
        acc_elem(a0.x, b0.x, hN, hP, hT);
        acc_elem(a0.y, b0.y, hN, hP, hT);
        acc_elem(a0.z, b0.z, hN, hP, hT);
        acc_elem(a0.w, b0.w, hN, hP, hT);
        acc_elem(a1.x, b1.x, hN, hP, hT);
        acc_elem(a1.y, b1.y, hN, hP, hT);
        acc_elem(a1.z, b1.z, hN, hP, hT);
        acc_elem(a1.w, b1.w, hN, hP, hT);
    }
    for (; i0 < n4; i0 += stride) {
        float4 a0 = p4[i0];
        float4 b0 = t4[i0];
        acc_elem(a0.x, b0.x, hN, hP, hT);
        acc_elem(a0.y, b0.y, hN, hP, hT);
        acc_elem(a0.z, b0.z, hN, hP, hT);
        acc_elem(a0.w, b0.w, hN, hP, hT);
    }

    __syncthreads();

    float* dst = partials + (size_t)blockIdx.x * NH;
    for (int i = threadIdx.x; i < NB; i += BLOCK) {
        dst[i]          = hN[i];
        dst[NB + i]     = hP[i];
        dst[2 * NB + i] = hT[i];
    }
}

// Sum partials[nblk][NH] -> hist[NH]; one thread per column, coalesced reads.
__global__ __launch_bounds__(BLOCK) void ace_reduce(const float* __restrict__ partials,
                                                    float* __restrict__ hist,
                                                    int nblk) {
    int col = blockIdx.x * BLOCK + threadIdx.x;
    if (col >= NH) return;
    float s = 0.f;
    for (int b = 0; b < nblk; ++b) s += partials[(size_t)b * NH + col];
    hist[col] = s;
}

// 20-bin soft-ACE over the 1024-bucket histogram, first-order corrected.
__global__ __launch_bounds__(BLOCK) void ace_final(const float* __restrict__ hist,
                                                   float* __restrict__ out) {
    const float* HN = hist;
    const float* HP = hist + NB;
    const float* HT = hist + 2 * NB;

    float Sw[NUM_BINS], Sp[NUM_BINS], St[NUM_BINS];
#pragma unroll
    for (int j = 0; j < NUM_BINS; ++j) { Sw[j] = 0.f; Sp[j] = 0.f; St[j] = 0.f; }

    for (int b = threadIdx.x; b < NB; b += BLOCK) {
        float n  = HN[b];
        float P  = HP[b];
        float T  = HT[b];
        float m  = ((float)b + 0.5f) * (1.0f / (float)NB);
        float dp = P - m * n;              // sum of (p - m) within bucket
#pragma unroll
        for (int j = 0; j < NUM_BINS; ++j) {
            float c  = (float)j * (1.0f / 19.0f);
            float d  = m - c;
            float w  = __builtin_amdgcn_exp2f(K1C * d * d);   // exp(-d^2/T)
            float wd = w * (-20.0f * d);                      // dw/dm  (2/T = 20)
            Sw[j] += w * n + wd * dp;                         // sum w
            Sp[j] += w * P + wd * m * dp;                     // sum w*p (1st order)
            St[j] += w * T;                                   // sum w*t (0th order)
        }
    }

    // wave(64) tree reduction, then cross-wave via LDS
#pragma unroll
    for (int j = 0; j < NUM_BINS; ++j) {
#pragma unroll
        for (int off = 32; off > 0; off >>= 1) {
            Sw[j] += __shfl_down(Sw[j], off, 64);
            Sp[j] += __shfl_down(Sp[j], off, 64);
            St[j] += __shfl_down(St[j], off, 64);
        }
    }

    __shared__ float red[BLOCK / 64][3 * NUM_BINS];
    int wave = threadIdx.x >> 6;
    int lane = threadIdx.x & 63;
    if (lane == 0) {
#pragma unroll
        for (int j = 0; j < NUM_BINS; ++j) {
            red[wave][j]                = Sw[j];
            red[wave][NUM_BINS + j]     = Sp[j];
            red[wave][2 * NUM_BINS + j] = St[j];
        }
    }
    __syncthreads();

    if (threadIdx.x == 0) {
        float acc = 0.f;
        for (int j = 0; j < NUM_BINS; ++j) {
            float sw = 0.f, sp = 0.f, st = 0.f;
#pragma unroll
            for (int w = 0; w < BLOCK / 64; ++w) {
                sw += red[w][j];
                sp += red[w][NUM_BINS + j];
                st += red[w][2 * NUM_BINS + j];
            }
            float denom = sw + 1e-8f;
            float e = sp / denom;
            float o = st / denom;
            acc += (sw == 0.0f) ? 0.0f : fabsf(e - o);
        }
        out[0] = acc / (float)NUM_BINS;
    }
}

extern "C" void kernel_launch(void* const* d_in, const int* in_sizes, int n_in,
                              void* d_out, int out_size, void* d_ws, size_t ws_size,
                              hipStream_t stream) {
    const float* preds   = (const float*)d_in[0];
    const float* targets = (const float*)d_in[1];
    float* out           = (float*)d_out;

    int n  = in_sizes[0];
    int n4 = n >> 2;   // N = 32*1024*1024, divisible by 4

    // Size the grid to the workspace: (nblk+1) histograms of NH floats must fit.
    size_t histBytes = (size_t)NH * sizeof(float);
    long nblk = (long)(ws_size / histBytes) - 1;
    if (nblk > MAXBLK) nblk = MAXBLK;
    if (nblk < 1) nblk = 1;

    float* partials = (float*)d_ws;                       // [nblk][NH]
    float* hist     = partials + (size_t)nblk * NH;       // [NH]

    ace_hist<<<(int)nblk, BLOCK, 0, stream>>>(preds, targets, partials, n4, (int)nblk);
    ace_reduce<<<(NH + BLOCK - 1) / BLOCK, BLOCK, 0, stream>>>(partials, hist, (int)nblk);
    ace_final<<<1, BLOCK, 0, stream>>>(hist, out);
}

// Round 4
// 319.413 us; speedup vs baseline: 2.8915x; 2.8915x over previous
//
#include <hip/hip_runtime.h>
#include <math.h>

#define NUM_BINS 20
#define NPAIR    (NUM_BINS / 2)   // 10 packed bin-pairs
#define NACC     (3 * NUM_BINS)   // 60 scalar partials per block
#define BLOCK    256
#define MAXBLK   2048

typedef float vf2 __attribute__((ext_vector_type(2)));

// w_j(p) = exp(-(p - c_j)^2 / T) = exp2(K1*p*p) * exp2(K2*p)^j * exp2(K1*c_j*c_j)
//   K1 = -1/(T*ln2), K2 = 2/(19*T*ln2), T = 0.1, c_j = j/19
__device__ __host__ constexpr float K1f() { return (float)(-1.0 / (0.1 * 0.6931471805599453)); }
__device__ __host__ constexpr float K2f() { return (float)( 2.0 / (1.9 * 0.6931471805599453)); }

__global__ __launch_bounds__(BLOCK, 4) void ace_partial(const float* __restrict__ p,
                                                        const float* __restrict__ t,
                                                        float* __restrict__ partials,
                                                        int n4, int nblk) {
    const float K1 = K1f();
    const float K2 = K2f();

    // Bin-pair packed accumulators: lane .x = bin 2k, lane .y = bin 2k+1
    vf2 aW[NPAIR], aP[NPAIR], aT[NPAIR];
#pragma unroll
    for (int k = 0; k < NPAIR; ++k) {
        aW[k] = (vf2)(0.f);
        aP[k] = (vf2)(0.f);
        aT[k] = (vf2)(0.f);
    }

    const float4* __restrict__ p4 = (const float4*)p;
    const float4* __restrict__ t4 = (const float4*)t;

    int tid    = blockIdx.x * BLOCK + threadIdx.x;
    int stride = nblk * BLOCK;

    // Body for one (p-float4, t-float4) pair, fully unrolled
    auto body = [&](float4 pv, float4 tv) {
        float pe[4] = {pv.x, pv.y, pv.z, pv.w};
        float te[4] = {tv.x, tv.y, tv.z, tv.w};
#pragma unroll
        for (int e = 0; e < 4; ++e) {
            float pp = pe[e];
            float tt = te[e];
            float u  = __builtin_amdgcn_exp2f(K1 * pp * pp);  // exp(-p^2/T)
            float G  = __builtin_amdgcn_exp2f(K2 * pp);       // exp(2p/(19T))
            float G2 = G * G;
            vf2 gv;  gv.x = u;  gv.y = u * G;                 // (u*G^0, u*G^1)
            vf2 G2v; G2v.x = G2; G2v.y = G2;
            vf2 ppv; ppv.x = pp; ppv.y = pp;
            vf2 ttv; ttv.x = tt; ttv.y = tt;
#pragma unroll
            for (int k = 0; k < NPAIR; ++k) {
                aW[k] += gv;                                        // v_pk_add_f32
                aP[k]  = __builtin_elementwise_fma(gv, ppv, aP[k]); // v_pk_fma_f32
                aT[k]  = __builtin_elementwise_fma(gv, ttv, aT[k]); // v_pk_fma_f32
                gv    *= G2v;                                       // v_pk_mul_f32
            }
        }
    };

    // 2-deep batching: 4 independent dwordx4 loads in flight before any compute
    int i0 = tid;
    for (; i0 + stride < n4; i0 += 2 * stride) {
        float4 a0 = p4[i0];
        float4 b0 = t4[i0];
        float4 a1 = p4[i0 + stride];
        float4 b1 = t4[i0 + stride];
        body(a0, b0);
        body(a1, b1);
    }
    for (; i0 < n4; i0 += stride) {
        float4 a0 = p4[i0];
        float4 b0 = t4[i0];
        body(a0, b0);
    }

    // Wave(64)-level tree reduction (once per kernel — cost negligible)
#pragma unroll
    for (int k = 0; k < NPAIR; ++k) {
#pragma unroll
        for (int off = 32; off > 0; off >>= 1) {
            vf2 oW, oP, oT;
            oW.x = __shfl_down(aW[k].x, off, 64); oW.y = __shfl_down(aW[k].y, off, 64);
            oP.x = __shfl_down(aP[k].x, off, 64); oP.y = __shfl_down(aP[k].y, off, 64);
            oT.x = __shfl_down(aT[k].x, off, 64); oT.y = __shfl_down(aT[k].y, off, 64);
            aW[k] += oW; aP[k] += oP; aT[k] += oT;
        }
    }

    __shared__ float red[BLOCK / 64][NACC];
    int wave = threadIdx.x >> 6;
    int lane = threadIdx.x & 63;
    if (lane == 0) {
#pragma unroll
        for (int k = 0; k < NPAIR; ++k) {
            red[wave][2 * k]                    = aW[k].x;
            red[wave][2 * k + 1]                = aW[k].y;
            red[wave][NUM_BINS + 2 * k]         = aP[k].x;
            red[wave][NUM_BINS + 2 * k + 1]     = aP[k].y;
            red[wave][2 * NUM_BINS + 2 * k]     = aT[k].x;
            red[wave][2 * NUM_BINS + 2 * k + 1] = aT[k].y;
        }
    }
    __syncthreads();

    if (threadIdx.x < NACC) {
        float s = 0.f;
#pragma unroll
        for (int w = 0; w < BLOCK / 64; ++w) s += red[w][threadIdx.x];
        partials[blockIdx.x * NACC + threadIdx.x] = s;
    }
}

__global__ __launch_bounds__(1024) void ace_final(const float* __restrict__ partials,
                                                  float* __restrict__ out, int nblk) {
    const float K1 = K1f();

    __shared__ float red[NACC][16];
    __shared__ float sums[NACC];
    int tid = threadIdx.x;

    if (tid < NACC * 16) {
        int j = tid >> 4;
        int k = tid & 15;
        float s = 0.f;
        for (int b = k; b < nblk; b += 16) s += partials[b * NACC + j];
        red[j][k] = s;
    }
    __syncthreads();

    if (tid < NACC) {
        float s = 0.f;
#pragma unroll
        for (int k = 0; k < 16; ++k) s += red[tid][k];
        sums[tid] = s;
    }
    __syncthreads();

    if (tid == 0) {
        float acc = 0.f;
        for (int j = 0; j < NUM_BINS; ++j) {
            float c    = (float)j / 19.0f;
            float A    = __builtin_amdgcn_exp2f(K1 * c * c);  // exp(-c^2/T)
            float wsum = A * sums[j];
            float denom = wsum + 1e-8f;
            float e    = (A * sums[NUM_BINS + j]) / denom;
            float o    = (A * sums[2 * NUM_BINS + j]) / denom;
            float contrib = (wsum == 0.0f) ? 0.0f : fabsf(e - o);
            acc += contrib;
        }
        out[0] = acc / (float)NUM_BINS;
    }
}

extern "C" void kernel_launch(void* const* d_in, const int* in_sizes, int n_in,
                              void* d_out, int out_size, void* d_ws, size_t ws_size,
                              hipStream_t stream) {
    const float* preds   = (const float*)d_in[0];
    const float* targets = (const float*)d_in[1];
    float* out           = (float*)d_out;

    int n  = in_sizes[0];
    int n4 = n >> 2;   // N = 32*1024*1024, divisible by 4

    // Size the grid to the workspace: nblk partial-vectors of NACC floats must fit.
    size_t rowBytes = (size_t)NACC * sizeof(float);
    long nblk = (long)(ws_size / rowBytes);
    if (nblk > MAXBLK) nblk = MAXBLK;
    if (nblk < 1) nblk = 1;

    float* partials = (float*)d_ws;   // [nblk][NACC]

    ace_partial<<<(int)nblk, BLOCK, 0, stream>>>(preds, targets, partials, n4, (int)nblk);
    ace_final<<<1, 1024, 0, stream>>>(partials, out, (int)nblk);
}